// Round 1
// baseline (59.076 us; speedup 1.0000x reference)
//
#include <hip/hip_runtime.h>
#include <math.h>

#define HD 256
#define NSEQ 512
#define BB 2
#define MROWS (BB * NSEQ) // 1024

// ---------------------------------------------------------------------------
// Generic small GEMM: C[M x N] = act(A @ W_rows^T + bias)
//   A: (M, 256) row-major. W: N rows with row stride ldw; dot over 256 cols.
//   Tile 32x32, BK=32, 256 threads, per-thread 2x2. 256 blocks -> full chip.
// ---------------------------------------------------------------------------
__global__ __launch_bounds__(256) void gemm_k(
    const float* __restrict__ A, const float* __restrict__ W, int ldw,
    const float* __restrict__ bias, float* __restrict__ C, int N, int relu)
{
    __shared__ float As[32][36]; // k-major: As[k][m], pad 36 -> conflict-free b64 reads
    __shared__ float Ws[32][36];

    const int t  = threadIdx.x;
    const int m0 = blockIdx.y * 32;
    const int n0 = blockIdx.x * 32;
    const int tx = t & 15, ty = t >> 4;

    float acc00 = 0.f, acc01 = 0.f, acc10 = 0.f, acc11 = 0.f;

    const int r  = t >> 3;       // 0..31  (tile row)
    const int c4 = (t & 7) * 4;  // 0..28  (k offset, float4)

    for (int k0 = 0; k0 < 256; k0 += 32) {
        float4 av = *(const float4*)(A + (size_t)(m0 + r) * 256 + k0 + c4);
        float4 wv = *(const float4*)(W + (size_t)(n0 + r) * ldw + k0 + c4);
        As[c4 + 0][r] = av.x; As[c4 + 1][r] = av.y;
        As[c4 + 2][r] = av.z; As[c4 + 3][r] = av.w;
        Ws[c4 + 0][r] = wv.x; Ws[c4 + 1][r] = wv.y;
        Ws[c4 + 2][r] = wv.z; Ws[c4 + 3][r] = wv.w;
        __syncthreads();
        #pragma unroll
        for (int k = 0; k < 32; ++k) {
            float2 a2 = *(const float2*)&As[k][ty * 2];
            float2 w2 = *(const float2*)&Ws[k][tx * 2];
            acc00 += a2.x * w2.x; acc01 += a2.x * w2.y;
            acc10 += a2.y * w2.x; acc11 += a2.y * w2.y;
        }
        __syncthreads();
    }

    const int m = m0 + ty * 2, n = n0 + tx * 2;
    const float b0 = bias ? bias[n] : 0.f;
    const float b1 = bias ? bias[n + 1] : 0.f;
    float v00 = acc00 + b0, v01 = acc01 + b1;
    float v10 = acc10 + b0, v11 = acc11 + b1;
    if (relu) {
        v00 = fmaxf(v00, 0.f); v01 = fmaxf(v01, 0.f);
        v10 = fmaxf(v10, 0.f); v11 = fmaxf(v11, 0.f);
    }
    *(float2*)(C + (size_t)m * N + n)       = make_float2(v00, v01);
    *(float2*)(C + (size_t)(m + 1) * N + n) = make_float2(v10, v11);
}

// ---------------------------------------------------------------------------
// Pairwise: out[b,i,j] = (j<i) ? sigmoid( sum_h relu(a[b,i,h]+c[b,j,h]) * w[h] + b2 ) : 0
//   (b_ep1 already folded into a as GEMM bias)
//   Tile: 32x32 (i,j) per block; per-thread 2x2; a/c tiles in LDS (stride 260).
// ---------------------------------------------------------------------------
__global__ __launch_bounds__(256) void pair_k(
    const float* __restrict__ Ap, const float* __restrict__ Cc,
    const float* __restrict__ wv, const float* __restrict__ b2p,
    float* __restrict__ out)
{
    const int b  = blockIdx.z;
    const int it = blockIdx.y, jt = blockIdx.x;
    const int i0 = it * 32, j0 = jt * 32;
    const int t  = threadIdx.x;
    float* outb = out + (size_t)b * NSEQ * NSEQ;

    if (jt > it) { // strictly above diagonal at tile granularity -> all masked
        const int rr = t >> 3, cc = (t & 7) * 4;
        *(float4*)(outb + (size_t)(i0 + rr) * NSEQ + j0 + cc) =
            make_float4(0.f, 0.f, 0.f, 0.f);
        return;
    }

    __shared__ float As[32][260]; // stride 260: a-reads broadcast, c-reads 2-way (free)
    __shared__ float Cs[32][260];
    __shared__ float ws[256];

    {
        const int rr = t >> 3;           // 0..31
        const int cb = (t & 7) * 32;     // 0..224
        const float* ap = Ap + ((size_t)(b * NSEQ + i0 + rr)) * 256 + cb;
        const float* cp = Cc + ((size_t)(b * NSEQ + j0 + rr)) * 256 + cb;
        #pragma unroll
        for (int q = 0; q < 32; q += 4) {
            *(float4*)&As[rr][cb + q] = *(const float4*)(ap + q);
            *(float4*)&Cs[rr][cb + q] = *(const float4*)(cp + q);
        }
        if (t < 64) *(float4*)&ws[t * 4] = *(const float4*)(wv + t * 4);
    }
    __syncthreads();

    const float bias2 = *b2p;
    const int ti = t >> 4, tj = t & 15;

    float s11 = 0.f, s12 = 0.f, s21 = 0.f, s22 = 0.f;
    #pragma unroll 4
    for (int h = 0; h < 256; h += 4) {
        float4 a1 = *(const float4*)&As[ti][h];
        float4 a2 = *(const float4*)&As[ti + 16][h];
        float4 c1 = *(const float4*)&Cs[tj][h];
        float4 c2 = *(const float4*)&Cs[tj + 16][h];
        float4 w4 = *(const float4*)&ws[h];
        float av1[4] = {a1.x, a1.y, a1.z, a1.w};
        float av2[4] = {a2.x, a2.y, a2.z, a2.w};
        float cv1[4] = {c1.x, c1.y, c1.z, c1.w};
        float cv2[4] = {c2.x, c2.y, c2.z, c2.w};
        float we[4]  = {w4.x, w4.y, w4.z, w4.w};
        #pragma unroll
        for (int e = 0; e < 4; ++e) {
            s11 += fmaxf(av1[e] + cv1[e], 0.f) * we[e];
            s12 += fmaxf(av1[e] + cv2[e], 0.f) * we[e];
            s21 += fmaxf(av2[e] + cv1[e], 0.f) * we[e];
            s22 += fmaxf(av2[e] + cv2[e], 0.f) * we[e];
        }
    }

    const int i1 = i0 + ti, i2 = i1 + 16;
    const int j1 = j0 + tj, j2 = j1 + 16;
    const float r11 = 1.f / (1.f + expf(-(s11 + bias2)));
    const float r12 = 1.f / (1.f + expf(-(s12 + bias2)));
    const float r21 = 1.f / (1.f + expf(-(s21 + bias2)));
    const float r22 = 1.f / (1.f + expf(-(s22 + bias2)));
    outb[(size_t)i1 * NSEQ + j1] = (j1 < i1) ? r11 : 0.f;
    outb[(size_t)i1 * NSEQ + j2] = (j2 < i1) ? r12 : 0.f;
    outb[(size_t)i2 * NSEQ + j1] = (j1 < i2) ? r21 : 0.f;
    outb[(size_t)i2 * NSEQ + j2] = (j2 < i2) ? r22 : 0.f;
}

extern "C" void kernel_launch(void* const* d_in, const int* in_sizes, int n_in,
                              void* d_out, int out_size, void* d_ws, size_t ws_size,
                              hipStream_t stream)
{
    (void)in_sizes; (void)n_in; (void)out_size; (void)ws_size;
    const float* X    = (const float*)d_in[0];
    // d_in[1] = step_mask (all ones, unused by reference output)
    const float* Wg1  = (const float*)d_in[2];
    const float* bg1  = (const float*)d_in[3];
    const float* Wg2  = (const float*)d_in[4];
    const float* bg2  = (const float*)d_in[5];
    const float* Wep1 = (const float*)d_in[6];
    const float* bep1 = (const float*)d_in[7];
    const float* wep2 = (const float*)d_in[8];
    const float* bep2 = (const float*)d_in[9];
    float* out = (float*)d_out;

    // workspace: h, f, a', c  (a' aliases h after h is dead) -> 3 MB
    float* hbuf = (float*)d_ws;              // 1024*256
    float* fbuf = hbuf + MROWS * HD;         // 1024*256
    float* cbuf = fbuf + MROWS * HD;         // 1024*256
    float* abuf = hbuf;                      // overwrite h (dead after GEMM2)

    const dim3 gg(8, 32), bb(256);
    // h = relu(X @ Wg1^T + bg1)
    hipLaunchKernelGGL(gemm_k, gg, bb, 0, stream, X, Wg1, 256, bg1, hbuf, 256, 1);
    // f = relu(h @ Wg2^T + bg2)
    hipLaunchKernelGGL(gemm_k, gg, bb, 0, stream, hbuf, Wg2, 256, bg2, fbuf, 256, 1);
    // a' = f @ Wa^T + b_ep1   (Wa = W_ep1[:, :256], row stride 512)
    hipLaunchKernelGGL(gemm_k, gg, bb, 0, stream, fbuf, Wep1, 512, bep1, abuf, 256, 0);
    // c  = f @ Wb^T           (Wb = W_ep1[:, 256:], row stride 512)
    hipLaunchKernelGGL(gemm_k, gg, bb, 0, stream, fbuf, Wep1 + 256, 512, nullptr, cbuf, 256, 0);
    // scores
    hipLaunchKernelGGL(pair_k, dim3(16, 16, 2), bb, 0, stream, abuf, cbuf, wep2, bep2, out);
}

// Round 2
// 55.378 us; speedup vs baseline: 1.0668x; 1.0668x over previous
//
#include <hip/hip_runtime.h>
#include <math.h>

#define HD 256
#define NSEQ 512
#define BB 2
#define MROWS (BB * NSEQ) // 1024

// ---------------------------------------------------------------------------
// GEMM: C[m, n] = act( sum_k A[m,k] * Wrow(n)[k] + bias[n] )
//   A: (M, 256) row-major, lda=256 fixed.
//   Wrow(n) = W + (n & 255)*ldw + (n >> 8)*colOff   (supports W_ep1 col-halves)
//   Tile 16(m) x 32(n), BK=32, 256 threads, per-thread 1x2.
//   Grid (N/32, M/16): N=256 -> 512 blocks (2/CU), N=512 -> 1024 blocks (4/CU).
//   Double-buffered staging: global->reg prefetch issued right after barrier.
// ---------------------------------------------------------------------------
__global__ __launch_bounds__(256) void gemm_k(
    const float* __restrict__ A, const float* __restrict__ W, int ldw, int colOff,
    const float* __restrict__ bias, int biasN,
    float* __restrict__ C, int ldc, int relu)
{
    __shared__ float As[16][36];  // m-major (b128 reads over k), 36 -> 16B-aligned rows
    __shared__ float Ws[32][34];  // k-major Ws[k][n], stride 34 -> conflict-free b64

    const int t  = threadIdx.x;
    const int m0 = blockIdx.y * 16;
    const int n0 = blockIdx.x * 32;

    // staging indices
    const int wr = t >> 3;         // 0..31: n-within-tile for W loads
    const int wc = (t & 7) * 4;    // k offset (float4)
    const int gn = n0 + wr;
    const float* wp = W + (size_t)(gn & 255) * ldw + (size_t)(gn >> 8) * colOff + wc;

    float4 wreg = *(const float4*)wp;
    float4 areg = make_float4(0.f, 0.f, 0.f, 0.f);
    const float* ap = A;  // only meaningful for t<128
    if (t < 128) {
        ap = A + (size_t)(m0 + (t >> 3)) * 256 + wc;
        areg = *(const float4*)ap;
    }

    const int tm = t >> 4;        // 0..15
    const int tn = (t & 15) * 2;  // 0..30
    float acc0 = 0.f, acc1 = 0.f;

    for (int s = 0; s < 8; ++s) {
        Ws[wc + 0][wr] = wreg.x; Ws[wc + 1][wr] = wreg.y;
        Ws[wc + 2][wr] = wreg.z; Ws[wc + 3][wr] = wreg.w;
        if (t < 128) *(float4*)&As[t >> 3][wc] = areg;
        __syncthreads();
        if (s < 7) { // prefetch next stage; latency hidden under compute below
            wreg = *(const float4*)(wp + (s + 1) * 32);
            if (t < 128) areg = *(const float4*)(ap + (s + 1) * 32);
        }
        #pragma unroll
        for (int kk = 0; kk < 32; kk += 4) {
            float4 a4 = *(const float4*)&As[tm][kk];
            float av[4] = {a4.x, a4.y, a4.z, a4.w};
            #pragma unroll
            for (int q = 0; q < 4; ++q) {
                float2 w2 = *(const float2*)&Ws[kk + q][tn];
                acc0 += av[q] * w2.x;
                acc1 += av[q] * w2.y;
            }
        }
        __syncthreads();
    }

    const int m = m0 + tm, n = n0 + tn;
    const float b0 = (bias && (n     < biasN)) ? bias[n]     : 0.f;
    const float b1 = (bias && (n + 1 < biasN)) ? bias[n + 1] : 0.f;
    float v0 = acc0 + b0, v1 = acc1 + b1;
    if (relu) { v0 = fmaxf(v0, 0.f); v1 = fmaxf(v1, 0.f); }
    *(float2*)(C + (size_t)m * ldc + n) = make_float2(v0, v1);
}

// ---------------------------------------------------------------------------
// Pairwise: out[b,i,j] = (j<i) ? sigmoid( sum_h relu(a[b,i,h]+c[b,j,h]) * w[h] + b2 ) : 0
//   AC: [B*N][512], a = cols 0-255 (b_ep1 pre-folded), c = cols 256-511.
//   Tile 32(i) x 16(j), 256 threads, per-thread 2x1. Grid (32, 16, B).
//   544 working blocks -> ~2.1 rounds; zero tiles exit after a 2-float store.
// ---------------------------------------------------------------------------
__global__ __launch_bounds__(256) void pair_k(
    const float* __restrict__ AC,
    const float* __restrict__ wv, const float* __restrict__ b2p,
    float* __restrict__ out)
{
    const int b  = blockIdx.z;
    const int it = blockIdx.y, jt = blockIdx.x;
    const int i0 = it * 32, j0 = jt * 16;
    const int t  = threadIdx.x;
    float* outb = out + (size_t)b * NSEQ * NSEQ;

    if (jt >= 2 * it + 2) { // j0 >= i0+31: tile fully masked
        const int r = t >> 3, c = (t & 7) * 2;
        *(float2*)(outb + (size_t)(i0 + r) * NSEQ + j0 + c) = make_float2(0.f, 0.f);
        return;
    }

    __shared__ float As[32][260]; // stride 260: a-reads 4-distinct, c-reads 2-way (free)
    __shared__ float Cs[16][260];
    __shared__ float ws[256];

    {
        const int r  = t >> 3;        // 0..31
        const int cb = (t & 7) * 32;  // 0..224
        const float* aptr = AC + (size_t)(b * NSEQ + i0 + r) * 512 + cb;
        #pragma unroll
        for (int q = 0; q < 32; q += 4)
            *(float4*)&As[r][cb + q] = *(const float4*)(aptr + q);
        if (t < 128) {
            const float* cptr = AC + (size_t)(b * NSEQ + j0 + r) * 512 + 256 + cb;
            #pragma unroll
            for (int q = 0; q < 32; q += 4)
                *(float4*)&Cs[r][cb + q] = *(const float4*)(cptr + q);
        }
        if (t < 64) *(float4*)&ws[t * 4] = *(const float4*)(wv + t * 4);
    }
    __syncthreads();

    const float bias2 = *b2p;
    const int ti = t >> 4, tj = t & 15;

    float s1 = 0.f, s2 = 0.f;
    #pragma unroll 8
    for (int h = 0; h < 256; h += 4) {
        float4 a1 = *(const float4*)&As[ti][h];
        float4 a2 = *(const float4*)&As[ti + 16][h];
        float4 cc = *(const float4*)&Cs[tj][h];
        float4 w4 = *(const float4*)&ws[h];
        s1 += fmaxf(a1.x + cc.x, 0.f) * w4.x + fmaxf(a1.y + cc.y, 0.f) * w4.y
            + fmaxf(a1.z + cc.z, 0.f) * w4.z + fmaxf(a1.w + cc.w, 0.f) * w4.w;
        s2 += fmaxf(a2.x + cc.x, 0.f) * w4.x + fmaxf(a2.y + cc.y, 0.f) * w4.y
            + fmaxf(a2.z + cc.z, 0.f) * w4.z + fmaxf(a2.w + cc.w, 0.f) * w4.w;
    }

    const int i1 = i0 + ti, i2 = i1 + 16;
    const int j  = j0 + tj;
    const float r1 = 1.f / (1.f + expf(-(s1 + bias2)));
    const float r2 = 1.f / (1.f + expf(-(s2 + bias2)));
    outb[(size_t)i1 * NSEQ + j] = (j < i1) ? r1 : 0.f;
    outb[(size_t)i2 * NSEQ + j] = (j < i2) ? r2 : 0.f;
}

extern "C" void kernel_launch(void* const* d_in, const int* in_sizes, int n_in,
                              void* d_out, int out_size, void* d_ws, size_t ws_size,
                              hipStream_t stream)
{
    (void)in_sizes; (void)n_in; (void)out_size; (void)ws_size;
    const float* X    = (const float*)d_in[0];
    // d_in[1] = step_mask (all ones; does not affect reference output)
    const float* Wg1  = (const float*)d_in[2];
    const float* bg1  = (const float*)d_in[3];
    const float* Wg2  = (const float*)d_in[4];
    const float* bg2  = (const float*)d_in[5];
    const float* Wep1 = (const float*)d_in[6];
    const float* bep1 = (const float*)d_in[7];
    const float* wep2 = (const float*)d_in[8];
    const float* bep2 = (const float*)d_in[9];
    float* out = (float*)d_out;

    float* hbuf  = (float*)d_ws;             // [1024][256]
    float* fbuf  = hbuf + MROWS * HD;        // [1024][256]
    float* acbuf = fbuf + MROWS * HD;        // [1024][512]: a | c

    const dim3 bb(256);
    // h = relu(X @ Wg1^T + bg1)
    hipLaunchKernelGGL(gemm_k, dim3(8, 64), bb, 0, stream,
                       X, Wg1, 256, 0, bg1, 256, hbuf, 256, 1);
    // f = relu(h @ Wg2^T + bg2)
    hipLaunchKernelGGL(gemm_k, dim3(8, 64), bb, 0, stream,
                       hbuf, Wg2, 256, 0, bg2, 256, fbuf, 256, 1);
    // [a | c] = f @ [Wa | Wb]^T, bias b_ep1 on a-half only
    hipLaunchKernelGGL(gemm_k, dim3(16, 64), bb, 0, stream,
                       fbuf, Wep1, 512, 256, bep1, 256, acbuf, 512, 0);
    // scores
    hipLaunchKernelGGL(pair_k, dim3(32, 16, 2), bb, 0, stream,
                       acbuf, wep2, bep2, out);
}